// Round 1
// baseline (311.242 us; speedup 1.0000x reference)
//
#include <hip/hip_runtime.h>
#include <hip/hip_bf16.h>

#define B_ 4
#define T_ 2048
#define D_ 512
#define H_ 8
#define M_ (B_*T_)   // 8192

typedef __attribute__((ext_vector_type(8))) short short8;
typedef __attribute__((ext_vector_type(4))) float float4v;
typedef unsigned short bf16_t;

__device__ __forceinline__ bf16_t f2bf(float f) {
  unsigned int u = __builtin_bit_cast(unsigned int, f);
  unsigned int r = (u + 0x7fffu + ((u >> 16) & 1u)) >> 16;
  return (bf16_t)r;
}

__device__ __forceinline__ float waveReduceSum(float v) {
#pragma unroll
  for (int m = 32; m >= 1; m >>= 1) v += __shfl_xor(v, m, 64);
  return v;
}

// ---------------- weight convert + transpose ----------------
// wqkvT[n][k] = w{q,k,v}[k][n] (bf16), wfcT[n][k] = wfc[k][n]
__global__ __launch_bounds__(256) void wconv_kernel(
    const float* __restrict__ wq, const float* __restrict__ wk,
    const float* __restrict__ wv, const float* __restrict__ wfc,
    bf16_t* __restrict__ wqkvT, bf16_t* __restrict__ wfcT) {
  for (int idx = blockIdx.x * 256 + threadIdx.x; idx < 1048576; idx += 262144) {
    if (idx < 786432) {
      int n = idx >> 9, k = idx & 511;
      const float* src = (n < 512) ? wq : ((n < 1024) ? wk : wv);
      int c = n & 511;
      wqkvT[idx] = f2bf(src[k * 512 + c]);
    } else {
      int j = idx - 786432;
      int n = j >> 9, k = j & 511;
      wfcT[j] = f2bf(wfc[k * 512 + n]);
    }
  }
}

// ---------------- LN1 + positional encoding ----------------
__global__ __launch_bounds__(256) void ln1_pe_kernel(
    const float* __restrict__ x, const float* __restrict__ g,
    const float* __restrict__ bb, float* __restrict__ h_f32,
    bf16_t* __restrict__ h_bf16) {
  int wave = threadIdx.x >> 6, lane = threadIdx.x & 63;
  int row = blockIdx.x * 4 + wave;
  int pos = row & (T_ - 1);
  const float* xr = x + (size_t)row * D_;
  int c0 = lane * 8;
  float v[8];
  float4 a = *(const float4*)(xr + c0);
  float4 b4 = *(const float4*)(xr + c0 + 4);
  v[0]=a.x; v[1]=a.y; v[2]=a.z; v[3]=a.w;
  v[4]=b4.x; v[5]=b4.y; v[6]=b4.z; v[7]=b4.w;
  float s = 0.f;
#pragma unroll
  for (int j = 0; j < 8; ++j) s += v[j];
  s = waveReduceSum(s);
  float mu = s * (1.f / 512.f);
  float q = 0.f;
#pragma unroll
  for (int j = 0; j < 8; ++j) { float d = v[j] - mu; q += d * d; }
  q = waveReduceSum(q);
  float rstd = rsqrtf(q * (1.f / 512.f) + 1e-5f);
  float* hr = h_f32 + (size_t)row * D_;
  bf16_t* hb = h_bf16 + (size_t)row * D_;
#pragma unroll
  for (int j = 0; j < 8; ++j) {
    int col = c0 + j;
    float hn = (v[j] - mu) * rstd * g[col] + bb[col];
    int i2 = (col >> 1) << 1;  // 2*i
    float dt = __expf((float)i2 * (-9.2103403719761836f / 512.0f));
    float ang = (float)pos * dt;
    float pe = (col & 1) ? __cosf(ang) : __sinf(ang);
    float hv = hn + pe;
    hr[col] = hv;
    hb[col] = f2bf(hv);
  }
}

// ---------------- GEMM: A[M][512] (bf16) x Bt[N][512] (bf16) -> C[M][N] ----------------
template <int N_COLS, bool OUT_BF16>
__global__ __launch_bounds__(256) void gemm_kernel(
    const bf16_t* __restrict__ A, const bf16_t* __restrict__ Bt,
    void* __restrict__ Cv) {
  __shared__ __align__(16) bf16_t As[64 * 72];
  __shared__ __align__(16) bf16_t Bs[64 * 72];
  const int m0 = blockIdx.y * 64;
  const int n0 = blockIdx.x * 64;
  const int tid = threadIdx.x;
  const int wave = tid >> 6, lane = tid & 63;
  const int ln = lane & 15, quad = lane >> 4;
  float4v acc[4];
  float4v z = {0.f, 0.f, 0.f, 0.f};
#pragma unroll
  for (int i = 0; i < 4; ++i) acc[i] = z;

  for (int k0 = 0; k0 < 512; k0 += 64) {
#pragma unroll
    for (int it = 0; it < 2; ++it) {
      int cid = tid + it * 256;
      int row = cid >> 3, cb = (cid & 7) << 3;
      short8 av = *(const short8*)(A + (size_t)(m0 + row) * 512 + k0 + cb);
      *(short8*)(As + row * 72 + cb) = av;
      short8 bv = *(const short8*)(Bt + (size_t)(n0 + row) * 512 + k0 + cb);
      *(short8*)(Bs + row * 72 + cb) = bv;
    }
    __syncthreads();
#pragma unroll
    for (int c = 0; c < 2; ++c) {
      short8 af = *(short8*)(As + (wave * 16 + ln) * 72 + c * 32 + quad * 8);
#pragma unroll
      for (int nt = 0; nt < 4; ++nt) {
        short8 bf = *(short8*)(Bs + (nt * 16 + ln) * 72 + c * 32 + quad * 8);
        acc[nt] = __builtin_amdgcn_mfma_f32_16x16x32_bf16(af, bf, acc[nt], 0, 0, 0);
      }
    }
    __syncthreads();
  }
#pragma unroll
  for (int nt = 0; nt < 4; ++nt) {
#pragma unroll
    for (int r = 0; r < 4; ++r) {
      int row = m0 + wave * 16 + quad * 4 + r;
      int col = n0 + nt * 16 + ln;
      if (OUT_BF16)
        ((bf16_t*)Cv)[(size_t)row * N_COLS + col] = f2bf(acc[nt][r]);
      else
        ((float*)Cv)[(size_t)row * N_COLS + col] = acc[nt][r];
    }
  }
}

// ---------------- flash-style causal attention ----------------
// qkv: [B*T][1536] bf16 (q | k | v interleaved by 512-col groups, head-major inside)
// out: [B*T][512] bf16
__global__ __launch_bounds__(256) void attn_kernel(const bf16_t* __restrict__ qkv,
                                                   bf16_t* __restrict__ out) {
  __shared__ __align__(16) bf16_t Ks[64 * 72];
  __shared__ __align__(16) bf16_t Vt[64 * 72];
  __shared__ __align__(16) bf16_t Ps[64 * 72];
  const int qt = blockIdx.x;
  const int bh = blockIdx.y;
  const int b = bh >> 3, h = bh & 7;
  const int tid = threadIdx.x;
  const int wave = tid >> 6, lane = tid & 63;
  const int ln = lane & 15, quad = lane >> 4;
  const size_t base = (size_t)b * T_ * 1536;
  const int qcol = h * 64, kcol = 512 + h * 64, vcol = 1024 + h * 64;

  short8 qf0, qf1;
  {
    size_t roff = base + (size_t)(qt * 64 + wave * 16 + ln) * 1536 + qcol;
    qf0 = *(const short8*)(qkv + roff + quad * 8);
    qf1 = *(const short8*)(qkv + roff + 32 + quad * 8);
  }
  float4v z = {0.f, 0.f, 0.f, 0.f};
  float4v oacc[4];
#pragma unroll
  for (int i = 0; i < 4; ++i) oacc[i] = z;
  float m_i[4] = {-1e30f, -1e30f, -1e30f, -1e30f};
  float l_i[4] = {0.f, 0.f, 0.f, 0.f};

  for (int kt = 0; kt <= qt; ++kt) {
    // stage K tile row-major, V tile transposed
#pragma unroll
    for (int it = 0; it < 2; ++it) {
      int cid = tid + it * 256;
      int row = cid >> 3, cb = (cid & 7) << 3;
      size_t roff = base + (size_t)(kt * 64 + row) * 1536;
      short8 kv8 = *(const short8*)(qkv + roff + kcol + cb);
      *(short8*)(Ks + row * 72 + cb) = kv8;
      short8 vv8 = *(const short8*)(qkv + roff + vcol + cb);
#pragma unroll
      for (int j = 0; j < 8; ++j) Vt[(cb + j) * 72 + row] = (bf16_t)vv8[j];
    }
    __syncthreads();

    // S = scale * Q K^T, causal mask on diagonal tile
    float ss[4][4];
#pragma unroll
    for (int nt = 0; nt < 4; ++nt) {
      float4v sa = z;
      short8 kf0 = *(short8*)(Ks + (nt * 16 + ln) * 72 + quad * 8);
      short8 kf1 = *(short8*)(Ks + (nt * 16 + ln) * 72 + 32 + quad * 8);
      sa = __builtin_amdgcn_mfma_f32_16x16x32_bf16(qf0, kf0, sa, 0, 0, 0);
      sa = __builtin_amdgcn_mfma_f32_16x16x32_bf16(qf1, kf1, sa, 0, 0, 0);
#pragma unroll
      for (int r = 0; r < 4; ++r) {
        float v = sa[r] * 0.125f;
        if (kt == qt) {
          int iloc = wave * 16 + quad * 4 + r;
          int jloc = nt * 16 + ln;
          if (jloc > iloc) v = -1e30f;
        }
        ss[nt][r] = v;
      }
    }
    // online softmax per row r (rows live across the 16 lanes of a quad)
    float alpha[4];
#pragma unroll
    for (int r = 0; r < 4; ++r) {
      float mx = fmaxf(fmaxf(ss[0][r], ss[1][r]), fmaxf(ss[2][r], ss[3][r]));
      mx = fmaxf(mx, __shfl_xor(mx, 1, 64));
      mx = fmaxf(mx, __shfl_xor(mx, 2, 64));
      mx = fmaxf(mx, __shfl_xor(mx, 4, 64));
      mx = fmaxf(mx, __shfl_xor(mx, 8, 64));
      float mn = fmaxf(m_i[r], mx);
      alpha[r] = __expf(m_i[r] - mn);
      m_i[r] = mn;
      float rs = 0.f;
#pragma unroll
      for (int nt = 0; nt < 4; ++nt) {
        float p = __expf(ss[nt][r] - mn);
        ss[nt][r] = p;
        rs += p;
      }
      rs += __shfl_xor(rs, 1, 64);
      rs += __shfl_xor(rs, 2, 64);
      rs += __shfl_xor(rs, 4, 64);
      rs += __shfl_xor(rs, 8, 64);
      l_i[r] = l_i[r] * alpha[r] + rs;
    }
#pragma unroll
    for (int d = 0; d < 4; ++d)
#pragma unroll
      for (int r = 0; r < 4; ++r) oacc[d][r] *= alpha[r];
    // P -> LDS (C-layout to A-layout relayout; same-wave rows only)
#pragma unroll
    for (int nt = 0; nt < 4; ++nt)
#pragma unroll
      for (int r = 0; r < 4; ++r)
        Ps[(wave * 16 + quad * 4 + r) * 72 + nt * 16 + ln] = f2bf(ss[nt][r]);
    // O += P V
#pragma unroll
    for (int c = 0; c < 2; ++c) {
      short8 pf = *(short8*)(Ps + (wave * 16 + ln) * 72 + c * 32 + quad * 8);
#pragma unroll
      for (int d = 0; d < 4; ++d) {
        short8 vf = *(short8*)(Vt + (d * 16 + ln) * 72 + c * 32 + quad * 8);
        oacc[d] = __builtin_amdgcn_mfma_f32_16x16x32_bf16(pf, vf, oacc[d], 0, 0, 0);
      }
    }
    __syncthreads();
  }
  // normalize + store
#pragma unroll
  for (int r = 0; r < 4; ++r) {
    float inv = 1.0f / l_i[r];
    int trow = qt * 64 + wave * 16 + quad * 4 + r;
    size_t o = ((size_t)(b * T_ + trow)) * 512 + h * 64;
#pragma unroll
    for (int d = 0; d < 4; ++d) out[o + d * 16 + ln] = f2bf(oacc[d][r] * inv);
  }
}

// ---------------- final LN + residuals ----------------
__global__ __launch_bounds__(256) void ln2_kernel(
    const float* __restrict__ o2, const float* __restrict__ hres,
    const float* __restrict__ x, const float* __restrict__ g,
    const float* __restrict__ bb, float* __restrict__ out) {
  int wave = threadIdx.x >> 6, lane = threadIdx.x & 63;
  int row = blockIdx.x * 4 + wave;
  size_t ro = (size_t)row * D_;
  int c0 = lane * 8;
  float t[8];
  float4 a0 = *(const float4*)(o2 + ro + c0);
  float4 a1 = *(const float4*)(o2 + ro + c0 + 4);
  float4 h0 = *(const float4*)(hres + ro + c0);
  float4 h1 = *(const float4*)(hres + ro + c0 + 4);
  t[0]=a0.x+h0.x; t[1]=a0.y+h0.y; t[2]=a0.z+h0.z; t[3]=a0.w+h0.w;
  t[4]=a1.x+h1.x; t[5]=a1.y+h1.y; t[6]=a1.z+h1.z; t[7]=a1.w+h1.w;
  float s = 0.f;
#pragma unroll
  for (int j = 0; j < 8; ++j) s += t[j];
  s = waveReduceSum(s);
  float mu = s * (1.f / 512.f);
  float q = 0.f;
#pragma unroll
  for (int j = 0; j < 8; ++j) { float d = t[j] - mu; q += d * d; }
  q = waveReduceSum(q);
  float rstd = rsqrtf(q * (1.f / 512.f) + 1e-6f);
#pragma unroll
  for (int j = 0; j < 8; ++j) {
    int col = c0 + j;
    out[ro + col] = (t[j] - mu) * rstd * g[col] + bb[col] + x[ro + col];
  }
}

// ---------------- launch ----------------
extern "C" void kernel_launch(void* const* d_in, const int* in_sizes, int n_in,
                              void* d_out, int out_size, void* d_ws, size_t ws_size,
                              hipStream_t stream) {
  const float* x   = (const float*)d_in[0];
  const float* g1  = (const float*)d_in[1];
  const float* b1  = (const float*)d_in[2];
  const float* wq  = (const float*)d_in[3];
  const float* wk  = (const float*)d_in[4];
  const float* wv  = (const float*)d_in[5];
  const float* wfc = (const float*)d_in[6];
  const float* g2  = (const float*)d_in[7];
  const float* b2  = (const float*)d_in[8];
  float* out = (float*)d_out;

  // workspace layout (bytes)
  char* ws = (char*)d_ws;
  const size_t O_HF32  = 0;                  // 8192*512*4  = 16777216
  const size_t O_HBF   = 16777216;           // 8192*512*2  =  8388608
  const size_t O_WQKV  = 25165824;           // 1536*512*2  =  1572864
  const size_t O_WFC   = 26738688;           //  512*512*2  =   524288
  const size_t O_QKV   = 27262976;           // 8192*1536*2 = 25165824
  const size_t O_ATTN  = 52428800;           // 8192*512*2  =  8388608
  const size_t O_O2    = 60817408;           // 8192*512*4  = 16777216
  const size_t WS_NEED = 77594624;
  if (ws_size < WS_NEED) return;

  float*  h_f32 = (float*)(ws + O_HF32);
  bf16_t* h_bf  = (bf16_t*)(ws + O_HBF);
  bf16_t* wqkvT = (bf16_t*)(ws + O_WQKV);
  bf16_t* wfcT  = (bf16_t*)(ws + O_WFC);
  bf16_t* qkv   = (bf16_t*)(ws + O_QKV);
  bf16_t* attn  = (bf16_t*)(ws + O_ATTN);
  float*  o2    = (float*)(ws + O_O2);

  wconv_kernel<<<dim3(1024), dim3(256), 0, stream>>>(wq, wk, wv, wfc, wqkvT, wfcT);
  ln1_pe_kernel<<<dim3(2048), dim3(256), 0, stream>>>(x, g1, b1, h_f32, h_bf);
  gemm_kernel<1536, true><<<dim3(24, 128), dim3(256), 0, stream>>>(h_bf, wqkvT, (void*)qkv);
  attn_kernel<<<dim3(32, 32), dim3(256), 0, stream>>>(qkv, attn);
  gemm_kernel<512, false><<<dim3(8, 128), dim3(256), 0, stream>>>(attn, wfcT, (void*)o2);
  ln2_kernel<<<dim3(2048), dim3(256), 0, stream>>>(o2, h_f32, x, g2, b2, out);
}

// Round 2
// 195.954 us; speedup vs baseline: 1.5883x; 1.5883x over previous
//
#include <hip/hip_runtime.h>
#include <hip/hip_bf16.h>

#define B_ 4
#define T_ 2048
#define D_ 512
#define H_ 8
#define M_ (B_*T_)   // 8192

typedef __attribute__((ext_vector_type(8))) short short8;
typedef __attribute__((ext_vector_type(4))) short short4v;
typedef __attribute__((ext_vector_type(4))) float float4v;
typedef unsigned short bf16_t;

__device__ __forceinline__ bf16_t f2bf(float f) {
  unsigned int u = __builtin_bit_cast(unsigned int, f);
  unsigned int r = (u + 0x7fffu + ((u >> 16) & 1u)) >> 16;
  return (bf16_t)r;
}

__device__ __forceinline__ float waveReduceSum(float v) {
#pragma unroll
  for (int m = 32; m >= 1; m >>= 1) v += __shfl_xor(v, m, 64);
  return v;
}

// ---------------- weight convert + transpose ----------------
__global__ __launch_bounds__(256) void wconv_kernel(
    const float* __restrict__ wq, const float* __restrict__ wk,
    const float* __restrict__ wv, const float* __restrict__ wfc,
    bf16_t* __restrict__ wqkvT, bf16_t* __restrict__ wfcT) {
  for (int idx = blockIdx.x * 256 + threadIdx.x; idx < 1048576; idx += 262144) {
    if (idx < 786432) {
      int n = idx >> 9, k = idx & 511;
      const float* src = (n < 512) ? wq : ((n < 1024) ? wk : wv);
      int c = n & 511;
      wqkvT[idx] = f2bf(src[k * 512 + c]);
    } else {
      int j = idx - 786432;
      int n = j >> 9, k = j & 511;
      wfcT[j] = f2bf(wfc[k * 512 + n]);
    }
  }
}

// ---------------- LN1 + positional encoding ----------------
__global__ __launch_bounds__(256) void ln1_pe_kernel(
    const float* __restrict__ x, const float* __restrict__ g,
    const float* __restrict__ bb, float* __restrict__ h_f32,
    bf16_t* __restrict__ h_bf16) {
  int wave = threadIdx.x >> 6, lane = threadIdx.x & 63;
  int row = blockIdx.x * 4 + wave;
  int pos = row & (T_ - 1);
  const float* xr = x + (size_t)row * D_;
  int c0 = lane * 8;
  float v[8];
  float4 a = *(const float4*)(xr + c0);
  float4 b4 = *(const float4*)(xr + c0 + 4);
  v[0]=a.x; v[1]=a.y; v[2]=a.z; v[3]=a.w;
  v[4]=b4.x; v[5]=b4.y; v[6]=b4.z; v[7]=b4.w;
  float s = 0.f;
#pragma unroll
  for (int j = 0; j < 8; ++j) s += v[j];
  s = waveReduceSum(s);
  float mu = s * (1.f / 512.f);
  float q = 0.f;
#pragma unroll
  for (int j = 0; j < 8; ++j) { float d = v[j] - mu; q += d * d; }
  q = waveReduceSum(q);
  float rstd = rsqrtf(q * (1.f / 512.f) + 1e-5f);
  float* hr = h_f32 + (size_t)row * D_;
  bf16_t* hb = h_bf16 + (size_t)row * D_;
#pragma unroll
  for (int j = 0; j < 8; ++j) {
    int col = c0 + j;
    float hn = (v[j] - mu) * rstd * g[col] + bb[col];
    int i2 = (col >> 1) << 1;
    float dt = __expf((float)i2 * (-9.2103403719761836f / 512.0f));
    float ang = (float)pos * dt;
    float pe = (col & 1) ? __cosf(ang) : __sinf(ang);
    float hv = hn + pe;
    hr[col] = hv;
    hb[col] = f2bf(hv);
  }
}

// ---------------- GEMM: A[M][512] (bf16) x Bt[N][512] (bf16) -> C[M][N] ----------------
template <int N_COLS, bool OUT_BF16>
__global__ __launch_bounds__(256) void gemm_kernel(
    const bf16_t* __restrict__ A, const bf16_t* __restrict__ Bt,
    void* __restrict__ Cv) {
  __shared__ __align__(16) bf16_t As[64 * 72];
  __shared__ __align__(16) bf16_t Bs[64 * 72];
  const int m0 = blockIdx.y * 64;
  const int n0 = blockIdx.x * 64;
  const int tid = threadIdx.x;
  const int wave = tid >> 6, lane = tid & 63;
  const int ln = lane & 15, quad = lane >> 4;
  float4v acc[4];
  float4v z = {0.f, 0.f, 0.f, 0.f};
#pragma unroll
  for (int i = 0; i < 4; ++i) acc[i] = z;

  for (int k0 = 0; k0 < 512; k0 += 64) {
#pragma unroll
    for (int it = 0; it < 2; ++it) {
      int cid = tid + it * 256;
      int row = cid >> 3, cb = (cid & 7) << 3;
      short8 av = *(const short8*)(A + (size_t)(m0 + row) * 512 + k0 + cb);
      *(short8*)(As + row * 72 + cb) = av;
      short8 bv = *(const short8*)(Bt + (size_t)(n0 + row) * 512 + k0 + cb);
      *(short8*)(Bs + row * 72 + cb) = bv;
    }
    __syncthreads();
#pragma unroll
    for (int c = 0; c < 2; ++c) {
      short8 af = *(short8*)(As + (wave * 16 + ln) * 72 + c * 32 + quad * 8);
#pragma unroll
      for (int nt = 0; nt < 4; ++nt) {
        short8 bf = *(short8*)(Bs + (nt * 16 + ln) * 72 + c * 32 + quad * 8);
        acc[nt] = __builtin_amdgcn_mfma_f32_16x16x32_bf16(af, bf, acc[nt], 0, 0, 0);
      }
    }
    __syncthreads();
  }
#pragma unroll
  for (int nt = 0; nt < 4; ++nt) {
#pragma unroll
    for (int r = 0; r < 4; ++r) {
      int row = m0 + wave * 16 + quad * 4 + r;
      int col = n0 + nt * 16 + ln;
      if (OUT_BF16)
        ((bf16_t*)Cv)[(size_t)row * N_COLS + col] = f2bf(acc[nt][r]);
      else
        ((float*)Cv)[(size_t)row * N_COLS + col] = acc[nt][r];
    }
  }
}

// ---------------- flash-style causal attention (S^T formulation) ----------------
// qk: [B*T][1024] bf16 (Q | K, head-major inside each 512 half)
// vT: [512][8192] bf16, row = h*64+d, col = b*T + t
// out: [B*T][512] bf16
__global__ __launch_bounds__(256) void attn_kernel(const bf16_t* __restrict__ qk,
                                                   const bf16_t* __restrict__ vT,
                                                   bf16_t* __restrict__ out) {
  __shared__ __align__(16) bf16_t Ks[2][64 * 72];
  __shared__ __align__(16) bf16_t Vs[2][64 * 72];
  __shared__ __align__(16) bf16_t Ps[4][16 * 72];
  const int bx = blockIdx.x;
  const int qt = 31 - (bx >> 5);      // long blocks dispatch first
  const int bh = bx & 31;
  const int b = bh >> 3, h = bh & 7;
  const int tid = threadIdx.x;
  const int w = tid >> 6, lane = tid & 63;
  const int ln = lane & 15, quad = lane >> 4;
  const int srow = tid >> 3;           // 0..31 (staging row)
  const int scb = (tid & 7) << 3;      // 0..56 (staging col base)

  // Q fragments: B-operand rows = this wave's 16 q-rows
  short8 qf0, qf1;
  {
    size_t qrow = ((size_t)b * T_ + qt * 64 + w * 16 + ln) * 1024 + h * 64;
    qf0 = *(const short8*)(qk + qrow + quad * 8);
    qf1 = *(const short8*)(qk + qrow + 32 + quad * 8);
  }
  float4v z = {0.f, 0.f, 0.f, 0.f};
  float4v oacc[4];
#pragma unroll
  for (int i = 0; i < 4; ++i) oacc[i] = z;
  float m_s = -1e30f, l_s = 0.f;

  const size_t kcolbase = 512 + h * 64;
  const size_t vbase = (size_t)(h * 64) * 8192 + (size_t)b * T_;

  short8 kr0, kr1, vr0, vr1;
  // prefetch tile 0
  {
    size_t kb = ((size_t)b * T_) * 1024 + kcolbase;
    kr0 = *(const short8*)(qk + kb + (size_t)srow * 1024 + scb);
    kr1 = *(const short8*)(qk + kb + (size_t)(srow + 32) * 1024 + scb);
    vr0 = *(const short8*)(vT + vbase + (size_t)srow * 8192 + scb);
    vr1 = *(const short8*)(vT + vbase + (size_t)(srow + 32) * 8192 + scb);
  }
  *(short8*)(Ks[0] + srow * 72 + scb) = kr0;
  *(short8*)(Ks[0] + (srow + 32) * 72 + scb) = kr1;
  *(short8*)(Vs[0] + srow * 72 + scb) = vr0;
  *(short8*)(Vs[0] + (srow + 32) * 72 + scb) = vr1;
  __syncthreads();

  bf16_t* Psw = Ps[w];

  for (int kt = 0; kt <= qt; ++kt) {
    const int cur = kt & 1;
    const bool more = (kt < qt);
    if (more) {
      size_t kb = ((size_t)b * T_ + (kt + 1) * 64) * 1024 + kcolbase;
      kr0 = *(const short8*)(qk + kb + (size_t)srow * 1024 + scb);
      kr1 = *(const short8*)(qk + kb + (size_t)(srow + 32) * 1024 + scb);
      size_t vb = vbase + (kt + 1) * 64;
      vr0 = *(const short8*)(vT + vb + (size_t)srow * 8192 + scb);
      vr1 = *(const short8*)(vT + vb + (size_t)(srow + 32) * 8192 + scb);
    }
    // S^T = K Q^T : D[kpos][q]
    float sv[4][4];
#pragma unroll
    for (int mt = 0; mt < 4; ++mt) {
      float4v st = z;
      short8 a0 = *(short8*)(Ks[cur] + (mt * 16 + ln) * 72 + quad * 8);
      short8 a1 = *(short8*)(Ks[cur] + (mt * 16 + ln) * 72 + 32 + quad * 8);
      st = __builtin_amdgcn_mfma_f32_16x16x32_bf16(a0, qf0, st, 0, 0, 0);
      st = __builtin_amdgcn_mfma_f32_16x16x32_bf16(a1, qf1, st, 0, 0, 0);
#pragma unroll
      for (int r = 0; r < 4; ++r) {
        float v = st[r] * 0.125f;
        if (kt == qt) {
          int kloc = mt * 16 + quad * 4 + r;
          if (kloc > w * 16 + ln) v = -1e30f;
        }
        sv[mt][r] = v;
      }
    }
    // online softmax: q lives in lanes (ln), k in regs+quads
    float mx = sv[0][0];
#pragma unroll
    for (int mt = 0; mt < 4; ++mt)
#pragma unroll
      for (int r = 0; r < 4; ++r) mx = fmaxf(mx, sv[mt][r]);
    mx = fmaxf(mx, __shfl_xor(mx, 16, 64));
    mx = fmaxf(mx, __shfl_xor(mx, 32, 64));
    float mn = fmaxf(m_s, mx);
    float alpha = __expf(m_s - mn);
    m_s = mn;
    float rs = 0.f;
#pragma unroll
    for (int mt = 0; mt < 4; ++mt)
#pragma unroll
      for (int r = 0; r < 4; ++r) {
        float p = __expf(sv[mt][r] - mn);
        sv[mt][r] = p;
        rs += p;
      }
    rs += __shfl_xor(rs, 16, 64);
    rs += __shfl_xor(rs, 32, 64);
    l_s = l_s * alpha + rs;
#pragma unroll
    for (int dt = 0; dt < 4; ++dt)
#pragma unroll
      for (int r = 0; r < 4; ++r) oacc[dt][r] *= alpha;
    // P^T -> Ps (wave-private): Ps[q=ln][k]
#pragma unroll
    for (int mt = 0; mt < 4; ++mt) {
      short4v p4;
#pragma unroll
      for (int r = 0; r < 4; ++r) p4[r] = (short)f2bf(sv[mt][r]);
      *(short4v*)(Psw + ln * 72 + mt * 16 + quad * 4) = p4;
    }
    // O^T += V^T P : D[d][q]
    short8 bp0 = *(short8*)(Psw + ln * 72 + quad * 8);
    short8 bp1 = *(short8*)(Psw + ln * 72 + 32 + quad * 8);
#pragma unroll
    for (int dt = 0; dt < 4; ++dt) {
      short8 av0 = *(short8*)(Vs[cur] + (dt * 16 + ln) * 72 + quad * 8);
      short8 av1 = *(short8*)(Vs[cur] + (dt * 16 + ln) * 72 + 32 + quad * 8);
      oacc[dt] = __builtin_amdgcn_mfma_f32_16x16x32_bf16(av0, bp0, oacc[dt], 0, 0, 0);
      oacc[dt] = __builtin_amdgcn_mfma_f32_16x16x32_bf16(av1, bp1, oacc[dt], 0, 0, 0);
    }
    if (more) {
      const int nxt = cur ^ 1;
      *(short8*)(Ks[nxt] + srow * 72 + scb) = kr0;
      *(short8*)(Ks[nxt] + (srow + 32) * 72 + scb) = kr1;
      *(short8*)(Vs[nxt] + srow * 72 + scb) = vr0;
      *(short8*)(Vs[nxt] + (srow + 32) * 72 + scb) = vr1;
    }
    __syncthreads();
  }
  // epilogue: O[q][d] = O^T[d][q] / l
  float inv = 1.0f / l_s;
  size_t obase = ((size_t)b * T_ + qt * 64 + w * 16 + ln) * 512 + h * 64;
#pragma unroll
  for (int dt = 0; dt < 4; ++dt) {
    short4v o4;
#pragma unroll
    for (int r = 0; r < 4; ++r) o4[r] = (short)f2bf(oacc[dt][r] * inv);
    *(short4v*)(out + obase + dt * 16 + quad * 4) = o4;
  }
}

// ---------------- final LN + residuals ----------------
__global__ __launch_bounds__(256) void ln2_kernel(
    const float* __restrict__ o2, const float* __restrict__ hres,
    const float* __restrict__ x, const float* __restrict__ g,
    const float* __restrict__ bb, float* __restrict__ out) {
  int wave = threadIdx.x >> 6, lane = threadIdx.x & 63;
  int row = blockIdx.x * 4 + wave;
  size_t ro = (size_t)row * D_;
  int c0 = lane * 8;
  float t[8];
  float4 a0 = *(const float4*)(o2 + ro + c0);
  float4 a1 = *(const float4*)(o2 + ro + c0 + 4);
  float4 h0 = *(const float4*)(hres + ro + c0);
  float4 h1 = *(const float4*)(hres + ro + c0 + 4);
  t[0]=a0.x+h0.x; t[1]=a0.y+h0.y; t[2]=a0.z+h0.z; t[3]=a0.w+h0.w;
  t[4]=a1.x+h1.x; t[5]=a1.y+h1.y; t[6]=a1.z+h1.z; t[7]=a1.w+h1.w;
  float s = 0.f;
#pragma unroll
  for (int j = 0; j < 8; ++j) s += t[j];
  s = waveReduceSum(s);
  float mu = s * (1.f / 512.f);
  float q = 0.f;
#pragma unroll
  for (int j = 0; j < 8; ++j) { float d = t[j] - mu; q += d * d; }
  q = waveReduceSum(q);
  float rstd = rsqrtf(q * (1.f / 512.f) + 1e-6f);
#pragma unroll
  for (int j = 0; j < 8; ++j) {
    int col = c0 + j;
    out[ro + col] = (t[j] - mu) * rstd * g[col] + bb[col] + x[ro + col];
  }
}

// ---------------- launch ----------------
extern "C" void kernel_launch(void* const* d_in, const int* in_sizes, int n_in,
                              void* d_out, int out_size, void* d_ws, size_t ws_size,
                              hipStream_t stream) {
  const float* x   = (const float*)d_in[0];
  const float* g1  = (const float*)d_in[1];
  const float* b1  = (const float*)d_in[2];
  const float* wq  = (const float*)d_in[3];
  const float* wk  = (const float*)d_in[4];
  const float* wv  = (const float*)d_in[5];
  const float* wfc = (const float*)d_in[6];
  const float* g2  = (const float*)d_in[7];
  const float* b2  = (const float*)d_in[8];
  float* out = (float*)d_out;

  // workspace layout (bytes)
  char* ws = (char*)d_ws;
  const size_t O_HF32  = 0;                  // 8192*512*4  = 16777216
  const size_t O_HBF   = 16777216;           // 8192*512*2  =  8388608
  const size_t O_WQKV  = 25165824;           // 1536*512*2  =  1572864
  const size_t O_WFC   = 26738688;           //  512*512*2  =   524288
  const size_t O_QK    = 27262976;           // 8192*1024*2 = 16777216
  const size_t O_VT    = 44040192;           //  512*8192*2 =  8388608
  const size_t O_ATTN  = 52428800;           // 8192*512*2  =  8388608
  const size_t O_O2    = 60817408;           // 8192*512*4  = 16777216
  const size_t WS_NEED = 77594624;
  if (ws_size < WS_NEED) return;

  float*  h_f32 = (float*)(ws + O_HF32);
  bf16_t* h_bf  = (bf16_t*)(ws + O_HBF);
  bf16_t* wqkvT = (bf16_t*)(ws + O_WQKV);
  bf16_t* wfcT  = (bf16_t*)(ws + O_WFC);
  bf16_t* qk    = (bf16_t*)(ws + O_QK);
  bf16_t* vT    = (bf16_t*)(ws + O_VT);
  bf16_t* attn  = (bf16_t*)(ws + O_ATTN);
  float*  o2    = (float*)(ws + O_O2);

  wconv_kernel<<<dim3(1024), dim3(256), 0, stream>>>(wq, wk, wv, wfc, wqkvT, wfcT);
  ln1_pe_kernel<<<dim3(2048), dim3(256), 0, stream>>>(x, g1, b1, h_f32, h_bf);
  // Q|K projection: [8192][1024]
  gemm_kernel<1024, true><<<dim3(16, 128), dim3(256), 0, stream>>>(h_bf, wqkvT, (void*)qk);
  // V^T projection: [512][8192] (A = Wv^T rows of wqkvT, B = h)
  gemm_kernel<8192, true><<<dim3(128, 8), dim3(256), 0, stream>>>(wqkvT + 1024 * 512, h_bf, (void*)vT);
  attn_kernel<<<dim3(1024), dim3(256), 0, stream>>>(qk, vT, attn);
  gemm_kernel<512, false><<<dim3(8, 128), dim3(256), 0, stream>>>(attn, wfcT, (void*)o2);
  ln2_kernel<<<dim3(2048), dim3(256), 0, stream>>>(o2, h_f32, x, g2, b2, out);
}